// Round 2
// baseline (209.720 us; speedup 1.0000x reference)
//
#include <hip/hip_runtime.h>
#include <hip/hip_bf16.h>

// ScatterRouter: N=8192 tokens, E=8 experts, K=2, D=2048 (fp32 rows).
// Output (float32, flat): out_data[N*K][D], out_tags[N*K], counts[E].
// pos(token n, expert e) = base[e] + #{n' < n : e in top2(n')}.
//
// R2: 2 kernels. k_route = single-block fused top2 + packed scan + scatter of
// tok_of_pos/out_tags/counts. k_copy = wave-per-row gather copy, 8 float4/lane.

#define EXPERTS 8
#define TOPK 2
#define N_TOK 8192
#define NK (N_TOK * TOPK)
#define RT_THREADS 1024
#define TOK_PER_THR (N_TOK / RT_THREADS)   // 8
#define RT_WAVES (RT_THREADS / 64)          // 16

// ---------------- Kernel 1: fused routing (single block) ----------------
__global__ __launch_bounds__(RT_THREADS) void k_route(
        const float* __restrict__ gates,
        int* __restrict__ tok_of_pos,
        float* __restrict__ out_tags,
        float* __restrict__ counts_out) {
    const int t    = threadIdx.x;
    const int wave = t >> 6;
    const int lane = t & 63;

    // ---- top-2 per token; accumulate per-expert counts for this thread ----
    int mask[TOK_PER_THR];
    int cnt[EXPERTS];
    #pragma unroll
    for (int e = 0; e < EXPERTS; e++) cnt[e] = 0;

    const float4* g4 = (const float4*)gates;
    #pragma unroll
    for (int k = 0; k < TOK_PER_THR; k++) {
        int n = t * TOK_PER_THR + k;
        float4 a = g4[2 * n], b = g4[2 * n + 1];
        float v[EXPERTS] = {a.x, a.y, a.z, a.w, b.x, b.y, b.z, b.w};
        int e1 = 0; float b1 = v[0];
        #pragma unroll
        for (int e = 1; e < EXPERTS; e++) if (v[e] > b1) { b1 = v[e]; e1 = e; }
        int e2 = -1; float b2 = -1e30f;
        #pragma unroll
        for (int e = 0; e < EXPERTS; e++) if (e != e1 && v[e] > b2) { b2 = v[e]; e2 = e; }
        mask[k] = (1 << e1) | (1 << e2);
        cnt[e1]++; cnt[e2]++;
    }

    // ---- pack counts: pk[j] = cnt[2j] | cnt[2j+1]<<16 (fields never exceed 16384) ----
    int pk[4], incl[4];
    #pragma unroll
    for (int j = 0; j < 4; j++) pk[j] = cnt[2 * j] | (cnt[2 * j + 1] << 16);

    // ---- wave-level inclusive scan (shfl_up over 64 lanes) ----
    #pragma unroll
    for (int j = 0; j < 4; j++) incl[j] = pk[j];
    #pragma unroll
    for (int d = 1; d < 64; d <<= 1) {
        #pragma unroll
        for (int j = 0; j < 4; j++) {
            int up = __shfl_up(incl[j], d, 64);
            if (lane >= d) incl[j] += up;
        }
    }

    // ---- cross-wave scan via LDS ----
    __shared__ int wtot[RT_WAVES][4];
    if (lane == 63) {
        #pragma unroll
        for (int j = 0; j < 4; j++) wtot[wave][j] = incl[j];
    }
    __syncthreads();
    int wpref[4], tot[4];
    #pragma unroll
    for (int j = 0; j < 4; j++) { wpref[j] = 0; tot[j] = 0; }
    for (int w = 0; w < RT_WAVES; w++) {
        #pragma unroll
        for (int j = 0; j < 4; j++) {
            int x = wtot[w][j];
            if (w < wave) wpref[j] += x;
            tot[j] += x;
        }
    }

    // ---- expert totals + bases ----
    int tote[EXPERTS], base[EXPERTS];
    #pragma unroll
    for (int j = 0; j < 4; j++) {
        tote[2 * j]     = tot[j] & 0xFFFF;
        tote[2 * j + 1] = (tot[j] >> 16) & 0xFFFF;
    }
    int acc = 0;
    #pragma unroll
    for (int e = 0; e < EXPERTS; e++) { base[e] = acc; acc += tote[e]; }

    // ---- this thread's starting rank per expert ----
    int rank[EXPERTS];
    #pragma unroll
    for (int j = 0; j < 4; j++) {
        int excl = incl[j] - pk[j];           // exclusive within wave
        rank[2 * j]     = base[2 * j]     + ((wpref[j] + excl) & 0xFFFF);
        rank[2 * j + 1] = base[2 * j + 1] + (((wpref[j] + excl) >> 16) & 0xFFFF);
    }

    // ---- scatter positions ----
    #pragma unroll
    for (int k = 0; k < TOK_PER_THR; k++) {
        int n = t * TOK_PER_THR + k;
        int m = mask[k];
        #pragma unroll
        for (int e = 0; e < EXPERTS; e++) {
            if ((m >> e) & 1) {
                int pos = rank[e]++;
                tok_of_pos[pos] = n;
                out_tags[pos] = (float)n;
            }
        }
    }

    if (t < EXPERTS) counts_out[t] = (float)tote[t];
}

// ---------------- Kernel 2: wave-per-row gather copy ----------------
#define CP_BLOCKS 2048
#define CP_THREADS 256

__global__ __launch_bounds__(CP_THREADS) void k_copy(
        const float* __restrict__ in_flow,
        const int* __restrict__ tok_of_pos,
        float* __restrict__ out_data, int D) {
    const int lane   = threadIdx.x & 63;
    const int wid    = blockIdx.x * (CP_THREADS / 64) + (threadIdx.x >> 6);
    const int nwaves = CP_BLOCKS * (CP_THREADS / 64);   // 8192

    for (int p = wid; p < NK; p += nwaves) {
        int tok = tok_of_pos[p];                         // broadcast load
        const float4* src = (const float4*)(in_flow + (size_t)tok * D);
        float4*       dst = (float4*)(out_data + (size_t)p * D);
        float4 r[8];
        #pragma unroll
        for (int i = 0; i < 8; i++) r[i] = src[lane + 64 * i];   // 8 outstanding loads
        #pragma unroll
        for (int i = 0; i < 8; i++) dst[lane + 64 * i] = r[i];
    }
}

extern "C" void kernel_launch(void* const* d_in, const int* in_sizes, int n_in,
                              void* d_out, int out_size, void* d_ws, size_t ws_size,
                              hipStream_t stream) {
    const float* in_flow = (const float*)d_in[0];
    const float* gates   = (const float*)d_in[1];
    const int D = in_sizes[0] / N_TOK;                  // 2048

    int* tok_of_pos = (int*)d_ws;

    float* out_data   = (float*)d_out;
    float* out_tags   = out_data + (size_t)NK * D;
    float* counts_out = out_tags + NK;

    hipLaunchKernelGGL(k_route, dim3(1), dim3(RT_THREADS), 0, stream,
                       gates, tok_of_pos, out_tags, counts_out);
    hipLaunchKernelGGL(k_copy, dim3(CP_BLOCKS), dim3(CP_THREADS), 0, stream,
                       in_flow, tok_of_pos, out_data, D);
}

// Round 3
// 203.395 us; speedup vs baseline: 1.0311x; 1.0311x over previous
//
#include <hip/hip_runtime.h>
#include <hip/hip_bf16.h>

// ScatterRouter: N=8192 tokens, E=8 experts, K=2, D=2048 (fp32 rows).
// Output (float32, flat): out_data[N*K][D], out_tags[N*K], counts[E].
// pos(token n, expert e) = base[e] + #{n' < n : e in top2(n')}.
//
// R3: route emits pos_pair[n]=(p1,p2); copy reads each token row ONCE and
// writes it to both destinations (fetch 64 MB instead of 134 MB).

#define EXPERTS 8
#define TOPK 2
#define N_TOK 8192
#define NK (N_TOK * TOPK)
#define RT_THREADS 1024
#define TOK_PER_THR (N_TOK / RT_THREADS)   // 8
#define RT_WAVES (RT_THREADS / 64)          // 16

// ---------------- Kernel 1: fused routing (single block) ----------------
__global__ __launch_bounds__(RT_THREADS) void k_route(
        const float* __restrict__ gates,
        int2* __restrict__ pos_pair,
        float* __restrict__ counts_out) {
    const int t    = threadIdx.x;
    const int wave = t >> 6;
    const int lane = t & 63;

    // ---- top-2 per token; accumulate per-expert counts for this thread ----
    int mask[TOK_PER_THR];
    int cnt[EXPERTS];
    #pragma unroll
    for (int e = 0; e < EXPERTS; e++) cnt[e] = 0;

    const float4* g4 = (const float4*)gates;
    #pragma unroll
    for (int k = 0; k < TOK_PER_THR; k++) {
        int n = t * TOK_PER_THR + k;
        float4 a = g4[2 * n], b = g4[2 * n + 1];
        float v[EXPERTS] = {a.x, a.y, a.z, a.w, b.x, b.y, b.z, b.w};
        int e1 = 0; float b1 = v[0];
        #pragma unroll
        for (int e = 1; e < EXPERTS; e++) if (v[e] > b1) { b1 = v[e]; e1 = e; }
        int e2 = -1; float b2 = -1e30f;
        #pragma unroll
        for (int e = 0; e < EXPERTS; e++) if (e != e1 && v[e] > b2) { b2 = v[e]; e2 = e; }
        mask[k] = (1 << e1) | (1 << e2);
        cnt[e1]++; cnt[e2]++;
    }

    // ---- pack counts: pk[j] = cnt[2j] | cnt[2j+1]<<16 (fields <= 16384) ----
    int pk[4], incl[4];
    #pragma unroll
    for (int j = 0; j < 4; j++) pk[j] = cnt[2 * j] | (cnt[2 * j + 1] << 16);

    // ---- wave-level inclusive scan ----
    #pragma unroll
    for (int j = 0; j < 4; j++) incl[j] = pk[j];
    #pragma unroll
    for (int d = 1; d < 64; d <<= 1) {
        #pragma unroll
        for (int j = 0; j < 4; j++) {
            int up = __shfl_up(incl[j], d, 64);
            if (lane >= d) incl[j] += up;
        }
    }

    // ---- cross-wave scan via LDS ----
    __shared__ int wtot[RT_WAVES][4];
    if (lane == 63) {
        #pragma unroll
        for (int j = 0; j < 4; j++) wtot[wave][j] = incl[j];
    }
    __syncthreads();
    int wpref[4], tot[4];
    #pragma unroll
    for (int j = 0; j < 4; j++) { wpref[j] = 0; tot[j] = 0; }
    for (int w = 0; w < RT_WAVES; w++) {
        #pragma unroll
        for (int j = 0; j < 4; j++) {
            int x = wtot[w][j];
            if (w < wave) wpref[j] += x;
            tot[j] += x;
        }
    }

    // ---- expert totals + bases ----
    int tote[EXPERTS], base[EXPERTS];
    #pragma unroll
    for (int j = 0; j < 4; j++) {
        tote[2 * j]     = tot[j] & 0xFFFF;
        tote[2 * j + 1] = (tot[j] >> 16) & 0xFFFF;
    }
    int acc = 0;
    #pragma unroll
    for (int e = 0; e < EXPERTS; e++) { base[e] = acc; acc += tote[e]; }

    // ---- this thread's starting rank per expert ----
    int rank[EXPERTS];
    #pragma unroll
    for (int j = 0; j < 4; j++) {
        int excl = incl[j] - pk[j];           // exclusive within wave
        rank[2 * j]     = base[2 * j]     + ((wpref[j] + excl) & 0xFFFF);
        rank[2 * j + 1] = base[2 * j + 1] + (((wpref[j] + excl) >> 16) & 0xFFFF);
    }

    // ---- emit per-token position pair (coalesced 8x int2 per thread) ----
    #pragma unroll
    for (int k = 0; k < TOK_PER_THR; k++) {
        int n = t * TOK_PER_THR + k;
        int m = mask[k];
        int p[2]; int idx = 0;
        #pragma unroll
        for (int e = 0; e < EXPERTS; e++) {
            if ((m >> e) & 1) p[idx++] = rank[e]++;
        }
        pos_pair[n] = make_int2(p[0], p[1]);
    }

    if (t < EXPERTS) counts_out[t] = (float)tote[t];
}

// ---------------- Kernel 2: wave-per-token, read once, write twice ----------------
#define CP_THREADS 256
#define CP_BLOCKS (N_TOK / (CP_THREADS / 64))   // 2048 blocks -> 8192 waves

__global__ __launch_bounds__(CP_THREADS) void k_copy(
        const float* __restrict__ in_flow,
        const int2* __restrict__ pos_pair,
        float* __restrict__ out_data,
        float* __restrict__ out_tags, int D) {
    const int lane = threadIdx.x & 63;
    const int n    = blockIdx.x * (CP_THREADS / 64) + (threadIdx.x >> 6); // token

    int2 pp = pos_pair[n];

    const float4* src = (const float4*)(in_flow + (size_t)n * D);
    float4 r[8];
    #pragma unroll
    for (int i = 0; i < 8; i++) r[i] = src[lane + 64 * i];   // 8 KB row, once

    float4* dst1 = (float4*)(out_data + (size_t)pp.x * D);
    float4* dst2 = (float4*)(out_data + (size_t)pp.y * D);
    #pragma unroll
    for (int i = 0; i < 8; i++) dst1[lane + 64 * i] = r[i];
    #pragma unroll
    for (int i = 0; i < 8; i++) dst2[lane + 64 * i] = r[i];

    if (lane == 0) out_tags[pp.x] = (float)n;
    if (lane == 1) out_tags[pp.y] = (float)n;
}

extern "C" void kernel_launch(void* const* d_in, const int* in_sizes, int n_in,
                              void* d_out, int out_size, void* d_ws, size_t ws_size,
                              hipStream_t stream) {
    const float* in_flow = (const float*)d_in[0];
    const float* gates   = (const float*)d_in[1];
    const int D = in_sizes[0] / N_TOK;                  // 2048

    int2* pos_pair = (int2*)d_ws;

    float* out_data   = (float*)d_out;
    float* out_tags   = out_data + (size_t)NK * D;
    float* counts_out = out_tags + NK;

    hipLaunchKernelGGL(k_route, dim3(1), dim3(RT_THREADS), 0, stream,
                       gates, pos_pair, counts_out);
    hipLaunchKernelGGL(k_copy, dim3(CP_BLOCKS), dim3(CP_THREADS), 0, stream,
                       in_flow, pos_pair, out_data, out_tags, D);
}

// Round 5
// 201.996 us; speedup vs baseline: 1.0382x; 1.0069x over previous
//
#include <hip/hip_runtime.h>
#include <hip/hip_bf16.h>

// ScatterRouter: N=8192 tokens, E=8 experts, K=2, D=2048 (fp32 rows).
// Output (float32, flat): out_data[N*K][D], out_tags[N*K], counts[E].
// pos(token n, expert e) = base[e] + #{n' < n : e in top2(n')}.
//
// R5: R4 retry — nontemporal builtins need a NATIVE vector type, not
// HIP_vector_type<float,4>. Use ext_vector_type(4) float (same 16B layout).
// Traffic floor: 64 MB fetch (each in_flow row read once) + 134 MB write.

#define EXPERTS 8
#define TOPK 2
#define N_TOK 8192
#define NK (N_TOK * TOPK)
#define RT_THREADS 1024
#define TOK_PER_THR (N_TOK / RT_THREADS)   // 8
#define RT_WAVES (RT_THREADS / 64)          // 16

typedef float vfloat4 __attribute__((ext_vector_type(4)));  // native vector: ok for nontemporal builtins

// ---------------- Kernel 1: fused routing (single block) ----------------
__global__ __launch_bounds__(RT_THREADS) void k_route(
        const float* __restrict__ gates,
        int2* __restrict__ pos_pair,
        float* __restrict__ counts_out) {
    const int t    = threadIdx.x;
    const int wave = t >> 6;
    const int lane = t & 63;

    int mask[TOK_PER_THR];
    int cnt[EXPERTS];
    #pragma unroll
    for (int e = 0; e < EXPERTS; e++) cnt[e] = 0;

    const float4* g4 = (const float4*)gates;
    #pragma unroll
    for (int k = 0; k < TOK_PER_THR; k++) {
        int n = t * TOK_PER_THR + k;
        float4 a = g4[2 * n], b = g4[2 * n + 1];
        float v[EXPERTS] = {a.x, a.y, a.z, a.w, b.x, b.y, b.z, b.w};
        int e1 = 0; float b1 = v[0];
        #pragma unroll
        for (int e = 1; e < EXPERTS; e++) if (v[e] > b1) { b1 = v[e]; e1 = e; }
        int e2 = -1; float b2 = -1e30f;
        #pragma unroll
        for (int e = 0; e < EXPERTS; e++) if (e != e1 && v[e] > b2) { b2 = v[e]; e2 = e; }
        mask[k] = (1 << e1) | (1 << e2);
        cnt[e1]++; cnt[e2]++;
    }

    // pack counts: pk[j] = cnt[2j] | cnt[2j+1]<<16 (fields <= 16384)
    int pk[4], incl[4];
    #pragma unroll
    for (int j = 0; j < 4; j++) pk[j] = cnt[2 * j] | (cnt[2 * j + 1] << 16);

    // wave-level inclusive scan
    #pragma unroll
    for (int j = 0; j < 4; j++) incl[j] = pk[j];
    #pragma unroll
    for (int d = 1; d < 64; d <<= 1) {
        #pragma unroll
        for (int j = 0; j < 4; j++) {
            int up = __shfl_up(incl[j], d, 64);
            if (lane >= d) incl[j] += up;
        }
    }

    // cross-wave scan via LDS
    __shared__ int wtot[RT_WAVES][4];
    if (lane == 63) {
        #pragma unroll
        for (int j = 0; j < 4; j++) wtot[wave][j] = incl[j];
    }
    __syncthreads();
    int wpref[4], tot[4];
    #pragma unroll
    for (int j = 0; j < 4; j++) { wpref[j] = 0; tot[j] = 0; }
    for (int w = 0; w < RT_WAVES; w++) {
        #pragma unroll
        for (int j = 0; j < 4; j++) {
            int x = wtot[w][j];
            if (w < wave) wpref[j] += x;
            tot[j] += x;
        }
    }

    int tote[EXPERTS], base[EXPERTS];
    #pragma unroll
    for (int j = 0; j < 4; j++) {
        tote[2 * j]     = tot[j] & 0xFFFF;
        tote[2 * j + 1] = (tot[j] >> 16) & 0xFFFF;
    }
    int acc = 0;
    #pragma unroll
    for (int e = 0; e < EXPERTS; e++) { base[e] = acc; acc += tote[e]; }

    int rank[EXPERTS];
    #pragma unroll
    for (int j = 0; j < 4; j++) {
        int excl = incl[j] - pk[j];
        rank[2 * j]     = base[2 * j]     + ((wpref[j] + excl) & 0xFFFF);
        rank[2 * j + 1] = base[2 * j + 1] + (((wpref[j] + excl) >> 16) & 0xFFFF);
    }

    #pragma unroll
    for (int k = 0; k < TOK_PER_THR; k++) {
        int n = t * TOK_PER_THR + k;
        int m = mask[k];
        int p[2]; int idx = 0;
        #pragma unroll
        for (int e = 0; e < EXPERTS; e++) {
            if ((m >> e) & 1) p[idx++] = rank[e]++;
        }
        pos_pair[n] = make_int2(p[0], p[1]);
    }

    if (t < EXPERTS) counts_out[t] = (float)tote[t];
}

// ---------------- Kernel 2: wave-per-token, streaming read-once write-twice ----------------
#define CP_THREADS 256
#define CP_BLOCKS (N_TOK / (CP_THREADS / 64))   // 2048 blocks -> 8192 waves

__global__ __launch_bounds__(CP_THREADS) void k_copy(
        const float* __restrict__ in_flow,
        const int2* __restrict__ pos_pair,
        float* __restrict__ out_data,
        float* __restrict__ out_tags, int D) {
    const int lane = threadIdx.x & 63;
    const int n    = blockIdx.x * (CP_THREADS / 64) + (threadIdx.x >> 6); // token

    int2 pp = pos_pair[n];

    const vfloat4* src = (const vfloat4*)(in_flow + (size_t)n * D);
    vfloat4 r[8];
    #pragma unroll
    for (int i = 0; i < 8; i++)
        r[i] = __builtin_nontemporal_load(&src[lane + 64 * i]);  // read once, stream

    vfloat4* dst1 = (vfloat4*)(out_data + (size_t)pp.x * D);
    vfloat4* dst2 = (vfloat4*)(out_data + (size_t)pp.y * D);
    #pragma unroll
    for (int i = 0; i < 8; i++)
        __builtin_nontemporal_store(r[i], &dst1[lane + 64 * i]);
    #pragma unroll
    for (int i = 0; i < 8; i++)
        __builtin_nontemporal_store(r[i], &dst2[lane + 64 * i]);

    if (lane == 0) out_tags[pp.x] = (float)n;
    if (lane == 1) out_tags[pp.y] = (float)n;
}

extern "C" void kernel_launch(void* const* d_in, const int* in_sizes, int n_in,
                              void* d_out, int out_size, void* d_ws, size_t ws_size,
                              hipStream_t stream) {
    const float* in_flow = (const float*)d_in[0];
    const float* gates   = (const float*)d_in[1];
    const int D = in_sizes[0] / N_TOK;                  // 2048

    int2* pos_pair = (int2*)d_ws;

    float* out_data   = (float*)d_out;
    float* out_tags   = out_data + (size_t)NK * D;
    float* counts_out = out_tags + NK;

    hipLaunchKernelGGL(k_route, dim3(1), dim3(RT_THREADS), 0, stream,
                       gates, pos_pair, counts_out);
    hipLaunchKernelGGL(k_copy, dim3(CP_BLOCKS), dim3(CP_THREADS), 0, stream,
                       in_flow, pos_pair, out_data, out_tags, D);
}